// Round 4
// baseline (247.184 us; speedup 1.0000x reference)
//
#include <hip/hip_runtime.h>
#include <climits>

// StreamingRhythmProjector: B=4096 rows x U=2048 units.
// R12 (resubmit after infra timeout): two-row software pipeline per
// 256-thread block (grid = B/2 = 2048 = exactly 8 blocks/CU -> whole grid
// resident, one dispatch round).
// Theory: R9/R10/R11 all plateau at ~2.35 TB/s across different structures
// while fillBuffer hits 6.5 TB/s at 8.8% occupancy -> the limit is read-side
// MLP (Little's law: ~5 serial small round-trips per block), not a BW cap
// and not the store path (R11 falsified NT-store theory).
// Fixes here:
//  - batch 0 issues probe+open words for BOTH rows + row-0 chunk-0 data
//    (10 independent vmem) -> row-0 serial chain 5 trips -> ~3.
//  - row 1's visible/min_open/bval resolve during row-0 processing, so
//    row 1's whole pass-1 load set issues in ONE trip overlapped with
//    row-0 epilogue -> row-1 chain 5 trips -> ~1.
//  - per-row state stays at R9's 8+8 floats (rows sequential) to avoid
//    R10's scratch-spill trap; target VGPR <= 64 under launch_bounds(256,8).

constexpr int UNITS = 2048;
constexpr int BLOCK = 256;

typedef float f32x4 __attribute__((ext_vector_type(4)));

static __device__ __forceinline__ float waveSum(float v) {
#pragma unroll
  for (int m = 1; m < 64; m <<= 1) v += __shfl_xor(v, m, 64);
  return v;  // all lanes hold the sum
}

// First open index in [0, visible); chunk 0 ([0,256)) already in regs (o0).
static __device__ __forceinline__ int openScan(const int* __restrict__ open_run,
                                               size_t base, int ln, int visible,
                                               int4 o0) {
  {
    const int e = 4 * ln;
    int lm = INT_MAX;
    if (o0.w > 0 && e + 3 < visible) lm = e + 3;
    if (o0.z > 0 && e + 2 < visible) lm = e + 2;
    if (o0.y > 0 && e + 1 < visible) lm = e + 1;
    if (o0.x > 0 && e < visible)     lm = e;
    const unsigned long long bb = __ballot(lm != INT_MAX);
    if (bb) return __shfl(lm, (int)__ffsll(bb) - 1, 64);
  }
  for (int cs = 256; cs < visible; cs += 256) {  // rare (10% open density)
    const int e = cs + 4 * ln;
    int4 o4 = make_int4(0, 0, 0, 0);
    if (e < visible) o4 = *(const int4*)(open_run + base + e);
    int lm = INT_MAX;
    if (o4.w > 0 && e + 3 < visible) lm = e + 3;
    if (o4.z > 0 && e + 2 < visible) lm = e + 2;
    if (o4.y > 0 && e + 1 < visible) lm = e + 1;
    if (o4.x > 0 && e < visible)     lm = e;
    const unsigned long long bb = __ballot(lm != INT_MAX);
    if (bb) return __shfl(lm, (int)__ffsll(bb) - 1, 64);
  }
  return INT_MAX;
}

// sr/sc for 4 elements; returns via arrays, accumulates sums.
static __device__ __forceinline__ void chunkCompute(
    const float4& a4, const float4& l4, const float4& p4, const float4& b4,
    int e, int visible, float* sr_, float* sc_, float& sum_sr, float& sum_sc) {
  const float av[4] = {a4.x, a4.y, a4.z, a4.w};
  const float lv[4] = {l4.x, l4.y, l4.z, l4.w};
  const float pv[4] = {p4.x, p4.y, p4.z, p4.w};
  const float bv[4] = {b4.x, b4.y, b4.z, b4.w};
#pragma unroll
  for (int j = 0; j < 4; ++j) {
    const float m = (e + j < visible) ? 1.0f : 0.0f;
    const float a = fmaxf(av[j], 1.0f);                      // MIN_SPEECH_FRAMES
    const float sr = fmaxf(fminf(a * __expf(lv[j]), 3.0f * a), 1.0f) * m;
    const float sc = fmaxf(pv[j], 0.0f) * (0.5f + bv[j]) * m;
    sr_[j] = sr;
    sc_[j] = sc;
    sum_sr += sr;
    sum_sc += sc;
  }
}

// Everything after pass-1 compute: reduce, commit, scales, stores, tail.
static __device__ __forceinline__ void finishRow(
    const float* __restrict__ dur_anchor, const float* __restrict__ dur_logratio,
    const float* __restrict__ pause_weight, const float* __restrict__ boundary,
    const float* __restrict__ phase_ptr, const float* __restrict__ backlog,
    const float* __restrict__ clock_delta, float* __restrict__ out, int B,
    int row, size_t base, int t, int wv, int ln, int visible, int cand_pre,
    float bval, int prev, float sb, float pb, const float* sr_,
    const float* sc_, float sum_sr, float sum_sc, float (*sf)[4]) {
  const float w0 = waveSum(sum_sr);
  const float w1 = waveSum(sum_sc);
  if (ln == 0) { sf[0][wv] = w0; sf[1][wv] = w1; }
  __syncthreads();

  const float ts = sf[0][0] + sf[0][1] + sf[0][2] + sf[0][3];
  const float tc = sf[1][0] + sf[1][1] + sf[1][2] + sf[1][3];
  const float tm = (float)visible;

  int cand = cand_pre;
  if (cand > 0 && cand < visible && bval < 0.45f)     // BOUNDARY_COMMIT_THRESHOLD
    cand = max(prev, cand - 1);
  const int commit = max(prev, cand);

  const float sscale = sb / fmaxf(ts, 1e-6f);
  const bool usefb = !(tc > 0.0f);
  const float pscale = pb / fmaxf(tc, 1e-6f);
  const float fbw = pb / fmaxf(tm, 1.0f);
  const float eff_tot = usefb ? (sscale * ts + fbw * tm) : (sscale * ts + pscale * tc);

  float* __restrict__ out_speech = out;
  float* __restrict__ out_pause  = out + (size_t)B * UNITS;
  float* __restrict__ out_eff    = out + 2 * (size_t)B * UNITS;

#pragma unroll
  for (int c = 0; c < 2; ++c) {
    const int e0 = c * 1024 + 4 * t;
    f32x4 s4, q4, e4;
#pragma unroll
    for (int j = 0; j < 4; ++j) {
      const int k = c * 4 + j;
      const float m = (e0 + j < visible) ? 1.0f : 0.0f;
      const float speech = sr_[k] * sscale;            // sr already masked
      const float pause = usefb ? (m * fbw) : (sc_[k] * pscale);
      s4[j] = speech;
      q4[j] = pause;
      e4[j] = speech + pause;
    }
    *(f32x4*)(out_speech + base + e0) = s4;
    *(f32x4*)(out_pause  + base + e0) = q4;
    *(f32x4*)(out_eff    + base + e0) = e4;
  }

  // wave 0 alone: tiny [prev,commit) range sums (cache-hot recompute)
  if (wv == 0) {
    float src_rng = 0.f, eff_rng = 0.f;
    if (commit > prev) {
      for (int i = prev + ln; i < commit; i += 64) {   // all i < visible
        const float a = dur_anchor[base + i];
        const float l = dur_logratio[base + i];
        const float p = pause_weight[base + i];
        const float bo = boundary[base + i];
        src_rng += a;
        const float aa = fmaxf(a, 1.0f);
        const float sr = fmaxf(fminf(aa * __expf(l), 3.0f * aa), 1.0f);
        const float sc = fmaxf(p, 0.0f) * (0.5f + bo);
        eff_rng += sr * sscale + (usefb ? fbw : sc * pscale);
      }
    }
    const float srcp = waveSum(src_rng);
    const float execp = waveSum(eff_rng);

    if (ln == 0) {
      const float pp = phase_ptr[row];
      const float bl = backlog[row];
      const float cd = clock_delta[row];
      const bool adv = commit > prev;
      const float nclock = adv ? (cd + (execp - srcp)) : cd;
      const float nback = adv ? fmaxf(nclock, 0.0f) : bl;
      const float vt = fmaxf(eff_tot, 1.0f);
      const float nphase =
          adv ? fminf(fmaxf(pp + execp / vt, 0.0f), 1.0f) : pp;
      const size_t o = 3 * (size_t)B * UNITS;
      out[o + row] = (float)commit;
      out[o + (size_t)B + row] = nphase;
      out[o + 2 * (size_t)B + row] = nback;
      out[o + 3 * (size_t)B + row] = nclock;
    }
  }
}

__global__ __launch_bounds__(BLOCK, 8) void rhythm_kernel(
    const float* __restrict__ dur_anchor,    // [B,U]
    const float* __restrict__ unit_mask,     // [B,U] prefix mask (0/1)
    const float* __restrict__ speech_budget, // [B]
    const float* __restrict__ pause_budget,  // [B]
    const float* __restrict__ dur_logratio,  // [B,U]
    const float* __restrict__ pause_weight,  // [B,U]
    const float* __restrict__ boundary,      // [B,U]
    const float* __restrict__ phase_ptr,     // [B]
    const float* __restrict__ backlog,       // [B]
    const float* __restrict__ clock_delta,   // [B]
    const int*   __restrict__ commit_front,  // [B]
    const int*   __restrict__ open_run,      // [B,U]
    float* __restrict__ out,                 // f32, 3*B*U + 4*B
    int B) {
  const int nb = gridDim.x;
  const int r0 = blockIdx.x;
  const int r1 = blockIdx.x + nb;
  const bool has1 = (r1 < B);
  const int t = threadIdx.x;
  const int wv = t >> 6, ln = t & 63;
  const size_t base0 = (size_t)r0 * UNITS;
  const size_t base1 = (size_t)(has1 ? r1 : r0) * UNITS;  // safe alias if odd B

  __shared__ float sf0[2][4];
  __shared__ float sf1[2][4];

  // ---- batch 0: all independent first-trip loads, BOTH rows ----
  const int pi = 64 * ((ln < 32) ? ln : 0) + 63;
  const float v1_0 = unit_mask[base0 + pi];
  const float v1_1 = unit_mask[base1 + pi];
  const int4 oo0 = *(const int4*)(open_run + base0 + 4 * ln);
  const int4 oo1 = *(const int4*)(open_run + base1 + 4 * ln);
  const int e0 = 4 * t;            // chunk-0 element in [0,1024)
  const int e1 = 1024 + 4 * t;     // chunk-1 element in [1024,2048)
  const float4 a00 = *(const float4*)(dur_anchor   + base0 + e0);
  const float4 l00 = *(const float4*)(dur_logratio + base0 + e0);
  const float4 p00 = *(const float4*)(pause_weight + base0 + e0);
  const float4 b00 = *(const float4*)(boundary     + base0 + e0);

  // per-row scalars (tiny, cached)
  const int prev0 = commit_front[r0];
  const float sb0 = speech_budget[r0], pb0 = pause_budget[r0];

  // ---- resolve visible for BOTH rows (the two probe-2 loads overlap) ----
  int visible0, visible1;
  {
    const int c1 = __popcll(__ballot((ln < 32) && (v1_0 > 0.5f)));
    if (c1 == 32) {
      visible0 = 2048;
    } else {
      const int s = 64 * c1;
      const float v2 = unit_mask[base0 + s + ln];
      visible0 = s + __popcll(__ballot(v2 > 0.5f));
    }
  }
  {
    const int c1 = __popcll(__ballot((ln < 32) && (v1_1 > 0.5f)));
    if (c1 == 32) {
      visible1 = 2048;
    } else {
      const int s = 64 * c1;
      const float v2 = unit_mask[base1 + s + ln];
      visible1 = s + __popcll(__ballot(v2 > 0.5f));
    }
  }

  // ---- open scans + commit candidates + bval loads, BOTH rows ----
  const int mo0 = openScan(open_run, base0, ln, visible0, oo0);
  const int mo1 = openScan(open_run, base1, ln, visible1, oo1);
  const int closed0 = (mo0 == INT_MAX) ? visible0 : mo0;
  const int closed1 = (mo1 == INT_MAX) ? visible1 : mo1;
  const int cand0 = min(max(visible0 - 2, 0), closed0);   // TAIL_HOLD_UNITS
  const int cand1 = min(max(visible1 - 2, 0), closed1);
  const float bval0 = boundary[base0 + min(max(cand0 - 1, 0), UNITS - 1)];
  const float bval1 = boundary[base1 + min(max(cand1 - 1, 0), UNITS - 1)];

  // ---- row 0 pass 1 (chunk 0 from batch-0 regs; chunk 1 one more trip) ----
  float sr_[8], sc_[8];
  float sum_sr = 0.f, sum_sc = 0.f;
  chunkCompute(a00, l00, p00, b00, e0, visible0, sr_, sc_, sum_sr, sum_sc);
  if (e1 < visible0) {
    const float4 a4 = *(const float4*)(dur_anchor   + base0 + e1);
    const float4 l4 = *(const float4*)(dur_logratio + base0 + e1);
    const float4 p4 = *(const float4*)(pause_weight + base0 + e1);
    const float4 b4 = *(const float4*)(boundary     + base0 + e1);
    chunkCompute(a4, l4, p4, b4, e1, visible0, sr_ + 4, sc_ + 4, sum_sr, sum_sc);
  } else {
#pragma unroll
    for (int j = 0; j < 4; ++j) { sr_[4 + j] = 0.f; sc_[4 + j] = 0.f; }
  }

  finishRow(dur_anchor, dur_logratio, pause_weight, boundary, phase_ptr,
            backlog, clock_delta, out, B, r0, base0, t, wv, ln, visible0,
            cand0, bval0, prev0, sb0, pb0, sr_, sc_, sum_sr, sum_sc, sf0);

  // ---- row 1: visible1/mo1/bval1 already resolved; pass-1 loads are ONE
  //      trip, issued right after row-0 stores (overlap row-0 tail) ----
  if (has1) {
    const int prev1 = commit_front[r1];
    const float sb1 = speech_budget[r1], pb1 = pause_budget[r1];

    float tr_[8], tc_[8];
    float s_sr = 0.f, s_sc = 0.f;
    if (e0 < visible1) {
      const float4 a4 = *(const float4*)(dur_anchor   + base1 + e0);
      const float4 l4 = *(const float4*)(dur_logratio + base1 + e0);
      const float4 p4 = *(const float4*)(pause_weight + base1 + e0);
      const float4 b4 = *(const float4*)(boundary     + base1 + e0);
      chunkCompute(a4, l4, p4, b4, e0, visible1, tr_, tc_, s_sr, s_sc);
    } else {
#pragma unroll
      for (int j = 0; j < 4; ++j) { tr_[j] = 0.f; tc_[j] = 0.f; }
    }
    if (e1 < visible1) {
      const float4 a4 = *(const float4*)(dur_anchor   + base1 + e1);
      const float4 l4 = *(const float4*)(dur_logratio + base1 + e1);
      const float4 p4 = *(const float4*)(pause_weight + base1 + e1);
      const float4 b4 = *(const float4*)(boundary     + base1 + e1);
      chunkCompute(a4, l4, p4, b4, e1, visible1, tr_ + 4, tc_ + 4, s_sr, s_sc);
    } else {
#pragma unroll
      for (int j = 0; j < 4; ++j) { tr_[4 + j] = 0.f; tc_[4 + j] = 0.f; }
    }

    finishRow(dur_anchor, dur_logratio, pause_weight, boundary, phase_ptr,
              backlog, clock_delta, out, B, r1, base1, t, wv, ln, visible1,
              cand1, bval1, prev1, sb1, pb1, tr_, tc_, s_sr, s_sc, sf1);
  }
}

extern "C" void kernel_launch(void* const* d_in, const int* in_sizes, int n_in,
                              void* d_out, int out_size, void* d_ws, size_t ws_size,
                              hipStream_t stream) {
  const int B = in_sizes[7];  // phase_ptr length
  const int nb = (B + 1) / 2;
  rhythm_kernel<<<dim3(nb), dim3(BLOCK), 0, stream>>>(
      (const float*)d_in[0],   // dur_anchor_src
      (const float*)d_in[1],   // unit_mask
      (const float*)d_in[2],   // speech_budget_win
      (const float*)d_in[3],   // pause_budget_win
      (const float*)d_in[4],   // dur_logratio_unit
      (const float*)d_in[5],   // pause_weight_unit
      (const float*)d_in[6],   // boundary_latent
      (const float*)d_in[7],   // phase_ptr
      (const float*)d_in[8],   // backlog
      (const float*)d_in[9],   // clock_delta
      (const int*)d_in[10],    // commit_frontier
      (const int*)d_in[11],    // open_run_mask
      (float*)d_out, B);
}